// Round 1
// baseline (286.928 us; speedup 1.0000x reference)
//
#include <hip/hip_runtime.h>
#include <hip/hip_bf16.h>

#define SIZE 1024
#define NH 16
#define HD 64
#define BB 2
#define SS 2048
#define MROWS (BB * SS)  // 4096
#define QT 128           // attn q-tile
#define NQT (SS / QT)    // 16 q-tiles per (b,h)
#define NKT ((SS / 2) / 64)  // 16 k-tiles per S-half

using bf16 = __hip_bfloat16;
using frag16 = __attribute__((ext_vector_type(8))) short;   // 8 bf16 (4 VGPRs)
using frag4 = __attribute__((ext_vector_type(4))) short;    // 4 bf16 (2 VGPRs)
using f32x4 = __attribute__((ext_vector_type(4))) float;    // 4 fp32 acc
typedef unsigned int u32;

// async global->LDS, 16B per lane; lds dest = wave-uniform base + lane*16 (m97/m104)
__device__ __forceinline__ void glds16(const bf16* g, bf16* l) {
    __builtin_amdgcn_global_load_lds(
        (const __attribute__((address_space(1))) u32*)g,
        (__attribute__((address_space(3))) u32*)l, 16, 0, 0);
}

__device__ __forceinline__ void cvt_store8(bf16* dst, const float* src) {
    float4 a = *(const float4*)src;
    float4 b = *(const float4*)(src + 4);
    bf16 t[8];
    t[0] = __float2bfloat16(a.x); t[1] = __float2bfloat16(a.y);
    t[2] = __float2bfloat16(a.z); t[3] = __float2bfloat16(a.w);
    t[4] = __float2bfloat16(b.x); t[5] = __float2bfloat16(b.y);
    t[6] = __float2bfloat16(b.z); t[7] = __float2bfloat16(b.w);
    *(uint4*)dst = *(const uint4*)t;
}

// ---------------------------------------------------------------------------
// fp32 -> bf16 cast: z = 0..3 weights, z = 4..6 activations
// ---------------------------------------------------------------------------
__global__ __launch_bounds__(256) void cast_kernel(
    const float* __restrict__ Wq, const float* __restrict__ Wk,
    const float* __restrict__ Wv, const float* __restrict__ Wo,
    const float* __restrict__ q, const float* __restrict__ k,
    const float* __restrict__ v,
    bf16* __restrict__ Wb, bf16* __restrict__ qb,
    bf16* __restrict__ kb, bf16* __restrict__ vb)
{
    const int z = blockIdx.z;
    const float* s; bf16* d; int n;
    switch (z) {
        case 0: s = Wq; d = Wb;                   n = SIZE * SIZE;  break;
        case 1: s = Wk; d = Wb + SIZE * SIZE;     n = SIZE * SIZE;  break;
        case 2: s = Wv; d = Wb + 2 * SIZE * SIZE; n = SIZE * SIZE;  break;
        case 3: s = Wo; d = Wb + 3 * SIZE * SIZE; n = SIZE * SIZE;  break;
        case 4: s = q;  d = qb;                   n = MROWS * SIZE; break;
        case 5: s = k;  d = kb;                   n = MROWS * SIZE; break;
        default: s = v; d = vb;                   n = MROWS * SIZE; break;
    }
    const int i = (blockIdx.x * 256 + threadIdx.x) * 8;
    if (i < n) cvt_store8(d + i, s + i);
}

// ---------------------------------------------------------------------------
// m97-style qkv GEMM (R5-proven): 128x128 tile, BK=32, glds16 staging, bf16.
// vt_mode: epilogue transposes via LDS and writes vt[b][h][d][s] coalesced.
// ---------------------------------------------------------------------------
__device__ __forceinline__ void gemm_body(
    const bf16* __restrict__ X, const bf16* __restrict__ W,
    const float* __restrict__ bias, bf16* __restrict__ Y, float scale, bool vt_mode)
{
    __shared__ __align__(16) bf16 smem[8704];   // As[4096] | Bs[4096]; reused as tr[64][136]
    bf16* As = smem;
    bf16* Bs = smem + 4096;

    const int tid = threadIdx.x;
    const int wave = tid >> 6;
    const int lane = tid & 63;
    const int lane15 = lane & 15;
    const int quad = lane >> 4;
    const int bm = blockIdx.y * 128;
    const int bn = blockIdx.x * 128;
    const int wm = (wave & 1) * 64;
    const int wn = (wave >> 1) * 64;

    f32x4 acc[4][4];
#pragma unroll
    for (int i = 0; i < 4; i++)
#pragma unroll
        for (int j = 0; j < 4; j++)
            acc[i][j] = (f32x4){0.f, 0.f, 0.f, 0.f};

    const int srow = lane >> 2;        // 0..15 within chunk
    const int scol = (lane & 3) * 8;   // 0/8/16/24

    for (int kt = 0; kt < SIZE / 32; kt++) {
        const int k0 = kt * 32;
        __syncthreads();
#pragma unroll
        for (int n = 0; n < 2; n++) {
            const int c = wave * 2 + n;   // chunk 0..7, 16 rows each
            glds16(X + (size_t)(bm + c * 16 + srow) * SIZE + k0 + scol, As + c * 512);
            glds16(W + (size_t)(bn + c * 16 + srow) * SIZE + k0 + scol, Bs + c * 512);
        }
        __syncthreads();

        frag16 a[4], b[4];
#pragma unroll
        for (int mi = 0; mi < 4; mi++)
            a[mi] = *(const frag16*)(As + (wm + mi * 16 + lane15) * 32 + quad * 8);
#pragma unroll
        for (int ni = 0; ni < 4; ni++)
            b[ni] = *(const frag16*)(Bs + (wn + ni * 16 + lane15) * 32 + quad * 8);
#pragma unroll
        for (int mi = 0; mi < 4; mi++)
#pragma unroll
            for (int ni = 0; ni < 4; ni++)
                acc[mi][ni] = __builtin_amdgcn_mfma_f32_16x16x32_bf16(
                    a[mi], b[ni], acc[mi][ni], 0, 0, 0);
    }

    if (!vt_mode) {
        // C/D layout col=lane&15, row=quad*4+reg (m89/m91)
#pragma unroll
        for (int ni = 0; ni < 4; ni++) {
            const int col = bn + wn + ni * 16 + lane15;
            const float bv = bias[col];
#pragma unroll
            for (int mi = 0; mi < 4; mi++) {
                const int row = bm + wm + mi * 16 + quad * 4;
#pragma unroll
                for (int r = 0; r < 4; r++)
                    Y[(size_t)(row + r) * SIZE + col] =
                        __float2bfloat16((acc[mi][ni][r] + bv) * scale);
            }
        }
    } else {
        // transpose epilogue -> vt[b][h][d][s], coalesced 16B stores
        bf16* tr = smem;                   // [64][136]
        const int bloc = bm >> 11;
        const int s0g = bm & (SS - 1);
#pragma unroll
        for (int p = 0; p < 2; p++) {
            __syncthreads();
            if ((wave >> 1) == p) {
#pragma unroll
                for (int ni = 0; ni < 4; ni++) {
                    const int colp = ni * 16 + lane15;
                    const float bv = bias[bn + p * 64 + colp];
#pragma unroll
                    for (int mi = 0; mi < 4; mi++) {
                        const int row = wm + mi * 16 + quad * 4;
#pragma unroll
                        for (int r = 0; r < 4; r++)
                            tr[colp * 136 + row + r] =
                                __float2bfloat16(acc[mi][ni][r] + bv);
                    }
                }
            }
            __syncthreads();
            const int colp = tid >> 2;
            const int gcol = bn + p * 64 + colp;
            const int hh = gcol >> 6, dd = gcol & (HD - 1);
            bf16* dst = (bf16*)Y + ((size_t)(bloc * NH + hh) * HD + dd) * SS
                        + s0g + (tid & 3) * 32;
            const bf16* src = tr + colp * 136 + (tid & 3) * 32;
#pragma unroll
            for (int j = 0; j < 4; j++)
                *(uint4*)(dst + j * 8) = *(const uint4*)(src + j * 8);
        }
    }
}

__global__ __launch_bounds__(256) void qkv_proj_kernel(
    const bf16* __restrict__ qb, const bf16* __restrict__ kb, const bf16* __restrict__ vb,
    const bf16* __restrict__ Wb,
    const float* __restrict__ bq, const float* __restrict__ bk, const float* __restrict__ bv,
    bf16* __restrict__ qh, bf16* __restrict__ kh, bf16* __restrict__ vt)
{
    const bf16 *X, *W; const float* bi; bf16* Y; float sc; bool vm;
    if (blockIdx.z == 0)      { X = qb; W = Wb;                   bi = bq; Y = qh; sc = 0.125f; vm = false; }
    else if (blockIdx.z == 1) { X = kb; W = Wb + SIZE * SIZE;     bi = bk; Y = kh; sc = 1.0f;   vm = false; }
    else                      { X = vb; W = Wb + 2 * SIZE * SIZE; bi = bv; Y = vt; sc = 1.0f;   vm = true;  }
    gemm_body(X, W, bi, Y, sc, vm);
}

// ---------------------------------------------------------------------------
// Flash attention, split-S (2048 blocks = 8/CU after Ps elimination).
// S^T trick: compute S^T = K Q^T (swap MFMA operands) so the C-layout's 4
// regs/lane are 4 CONSECUTIVE KEYS at fixed q:
//   c[r] = S[q = m*16+lane15][key = nt*16 + quad*4 + r]
// That IS the A-fragment layout of v_mfma_f32_16x16x16_bf16 (A[m=lane15]
// [k=quad*4+e]) with nt as the K-tile -> PV and l=P@1 consume P STRAIGHT
// FROM REGISTERS. No Ps LDS buffer, no wave_barrier, no P round-trip:
// LDS 36864->18432 B => 8 blocks/CU (grid 2048 = fully resident).
// ---------------------------------------------------------------------------
__global__ __launch_bounds__(256) void attn_kernel(
    const bf16* __restrict__ qh, const bf16* __restrict__ kh,
    const bf16* __restrict__ vt, bf16* __restrict__ po, float* __restrict__ pl)
{
    __shared__ __align__(16) bf16 Ks[64][72];
    __shared__ __align__(16) bf16 Vs[64][72];

    const int tid = threadIdx.x;
    const int wave = tid >> 6;
    const int lane = tid & 63;
    const int lane15 = lane & 15;
    const int quad = lane >> 4;

    const int b = blockIdx.z, h = blockIdx.y;
    const int qt = blockIdx.x >> 1;
    const int sh = blockIdx.x & 1;
    const int q0 = qt * QT;

    const size_t baseq = (size_t)b * SS * SIZE + (size_t)h * HD;
    const size_t basev = (size_t)(b * NH + h) * HD * SS;
    const float LOG2E = 1.44269504088896340736f;
    const float OFF = 12.0f * LOG2E;

    frag16 aq[2][2];
#pragma unroll
    for (int m = 0; m < 2; m++) {
        const int qrow = q0 + wave * 32 + m * 16 + lane15;
        const bf16* qp = qh + baseq + (size_t)qrow * SIZE + quad * 8;
        aq[m][0] = *(const frag16*)(qp);
        aq[m][1] = *(const frag16*)(qp + 32);
    }

    frag4 ones4;
#pragma unroll
    for (int e = 0; e < 4; e++) ones4[e] = (short)0x3F80;   // bf16 1.0

    f32x4 ofrag[2][4], l_frag[2];
#pragma unroll
    for (int m = 0; m < 2; m++) {
        l_frag[m] = (f32x4){0.f, 0.f, 0.f, 0.f};
#pragma unroll
        for (int dt = 0; dt < 4; dt++) ofrag[m][dt] = (f32x4){0.f, 0.f, 0.f, 0.f};
    }

    const int sr = tid >> 3;          // 0..31
    const int sc = (tid & 7) * 8;

    for (int kt = 0; kt < NKT; kt++) {
        const int s0 = sh * (SS / 2) + kt * 64;
        __syncthreads();
        *(uint4*)&Ks[sr][sc]      = *(const uint4*)(kh + baseq + (size_t)(s0 + sr) * SIZE + sc);
        *(uint4*)&Ks[sr + 32][sc] = *(const uint4*)(kh + baseq + (size_t)(s0 + sr + 32) * SIZE + sc);
        *(uint4*)&Vs[sr][sc]      = *(const uint4*)(vt + basev + (size_t)sr * SS + s0 + sc);
        *(uint4*)&Vs[sr + 32][sc] = *(const uint4*)(vt + basev + (size_t)(sr + 32) * SS + s0 + sc);
        __syncthreads();

#pragma unroll
        for (int nt = 0; nt < 4; nt++) {
            // ---- S^T = K Q^T for this 16-key slice ----
            const frag16 kf0 = *(const frag16*)&Ks[nt * 16 + lane15][quad * 8];
            const frag16 kf1 = *(const frag16*)&Ks[nt * 16 + lane15][32 + quad * 8];
            frag4 pf[2];
#pragma unroll
            for (int m = 0; m < 2; m++) {
                f32x4 c = (f32x4){0.f, 0.f, 0.f, 0.f};
                c = __builtin_amdgcn_mfma_f32_16x16x32_bf16(kf0, aq[m][0], c, 0, 0, 0);
                c = __builtin_amdgcn_mfma_f32_16x16x32_bf16(kf1, aq[m][1], c, 0, 0, 0);
                // c[r] = S[q = m*16+lane15][key = nt*16 + quad*4 + r]
                bf16 p4[4];
#pragma unroll
                for (int r = 0; r < 4; r++)
                    p4[r] = __float2bfloat16(exp2f(fminf(c[r], 30.f) * LOG2E - OFF));
                pf[m] = *(const frag4*)p4;
            }

            // ---- l += P @ 1  (K=16 MFMA, P straight from regs) ----
#pragma unroll
            for (int m = 0; m < 2; m++)
                l_frag[m] = __builtin_amdgcn_mfma_f32_16x16x16bf16_1k(
                    pf[m], ones4, l_frag[m], 0, 0, 0);

            // ---- O += P V for this 16-key slice ----
            // B-frag: B[k=quad*4+e][n=lane15] = V[key=nt*16+quad*4+e][d=dt*16+lane15]
            //       = Vs[dt*16+lane15][nt*16+quad*4+e]  (Vs holds V^T as [d][s])
#pragma unroll
            for (int dt = 0; dt < 4; dt++) {
                const frag4 vf = *(const frag4*)&Vs[dt * 16 + lane15][nt * 16 + quad * 4];
#pragma unroll
                for (int m = 0; m < 2; m++)
                    ofrag[m][dt] = __builtin_amdgcn_mfma_f32_16x16x16bf16_1k(
                        pf[m], vf, ofrag[m][dt], 0, 0, 0);
            }
        }
    }

    // ---- partial outputs (un-normalized O + row sums) ----
    const int pb = ((b * NH + h) * NQT + qt) * 2 + sh;
    if (lane15 == 0) {
        float* plp = pl + (size_t)pb * QT;
#pragma unroll
        for (int m = 0; m < 2; m++)
#pragma unroll
            for (int r = 0; r < 4; r++)
                plp[wave * 32 + m * 16 + quad * 4 + r] = l_frag[m][r];
    }
    bf16* pop = po + (size_t)pb * QT * HD;
#pragma unroll
    for (int m = 0; m < 2; m++)
#pragma unroll
        for (int dt = 0; dt < 4; dt++)
#pragma unroll
            for (int r = 0; r < 4; r++)
                pop[(size_t)(wave * 32 + m * 16 + quad * 4 + r) * HD + dt * 16 + lane15] =
                    __float2bfloat16(ofrag[m][dt][r]);
}

// ---------------------------------------------------------------------------
// Combine the two S-halves: ctx = (po0 + po1) / (l0 + l1), write [b][s][h*64+d]
// ---------------------------------------------------------------------------
__global__ __launch_bounds__(256) void combine_kernel(
    const bf16* __restrict__ po, const float* __restrict__ pl, bf16* __restrict__ ctx)
{
    const int b = blockIdx.z, h = blockIdx.y, qt = blockIdx.x;
    const int tile = (b * NH + h) * NQT + qt;
    const bf16* p0 = po + (size_t)(tile * 2 + 0) * QT * HD;
    const bf16* p1 = po + (size_t)(tile * 2 + 1) * QT * HD;
    const int qr = threadIdx.x >> 1;
    const int dh = (threadIdx.x & 1) * 32;
    const float l = pl[(size_t)(tile * 2) * QT + qr] + pl[(size_t)(tile * 2 + 1) * QT + qr];
    const float inv = 1.0f / fmaxf(l, 1e-30f);
    bf16* dst = ctx + ((size_t)b * SS + qt * QT + qr) * SIZE + h * HD + dh;
    const bf16* s0p = p0 + qr * HD + dh;
    const bf16* s1p = p1 + qr * HD + dh;
#pragma unroll
    for (int j = 0; j < 32; j += 8) {
        uint4 u0 = *(const uint4*)(s0p + j);
        uint4 u1 = *(const uint4*)(s1p + j);
        const bf16* a = (const bf16*)&u0;
        const bf16* bt = (const bf16*)&u1;
        bf16 o[8];
#pragma unroll
        for (int e = 0; e < 8; e++)
            o[e] = __float2bfloat16((__bfloat162float(a[e]) + __bfloat162float(bt[e])) * inv);
        *(uint4*)(dst + j) = *(const uint4*)o;
    }
}

// ---------------------------------------------------------------------------
// Output projection: BM=64 x BN=128 -> 512 blocks = 2/CU (was 256 = 1/CU,
// zero barrier overlap). bf16 glds16 staging both operands. fp32 out.
// ---------------------------------------------------------------------------
__global__ __launch_bounds__(256) void out_proj_kernel(
    const bf16* __restrict__ ctx, const bf16* __restrict__ Wob,
    const float* __restrict__ bo, float* __restrict__ out)
{
    __shared__ __align__(16) bf16 As[64 * 32];
    __shared__ __align__(16) bf16 Bs[128 * 32];

    const int tid = threadIdx.x;
    const int wave = tid >> 6;
    const int lane = tid & 63;
    const int lane15 = lane & 15;
    const int quad = lane >> 4;
    const int bm = blockIdx.y * 64;
    const int bn = blockIdx.x * 128;
    const int wn = wave * 32;

    f32x4 acc[4][2];
#pragma unroll
    for (int i = 0; i < 4; i++)
#pragma unroll
        for (int j = 0; j < 2; j++)
            acc[i][j] = (f32x4){0.f, 0.f, 0.f, 0.f};

    const int srow = lane >> 2;        // 0..15 within chunk
    const int scol = (lane & 3) * 8;

    for (int kt = 0; kt < SIZE / 32; kt++) {
        const int k0 = kt * 32;
        __syncthreads();
        glds16(ctx + (size_t)(bm + wave * 16 + srow) * SIZE + k0 + scol, As + wave * 512);
#pragma unroll
        for (int n = 0; n < 2; n++) {
            const int c = wave * 2 + n;
            glds16(Wob + (size_t)(bn + c * 16 + srow) * SIZE + k0 + scol, Bs + c * 512);
        }
        __syncthreads();

        frag16 a[4], b[2];
#pragma unroll
        for (int mi = 0; mi < 4; mi++)
            a[mi] = *(const frag16*)(As + (mi * 16 + lane15) * 32 + quad * 8);
#pragma unroll
        for (int ni = 0; ni < 2; ni++)
            b[ni] = *(const frag16*)(Bs + (wn + ni * 16 + lane15) * 32 + quad * 8);
#pragma unroll
        for (int mi = 0; mi < 4; mi++)
#pragma unroll
            for (int ni = 0; ni < 2; ni++)
                acc[mi][ni] = __builtin_amdgcn_mfma_f32_16x16x32_bf16(
                    a[mi], b[ni], acc[mi][ni], 0, 0, 0);
    }

#pragma unroll
    for (int ni = 0; ni < 2; ni++) {
        const int col = bn + wn + ni * 16 + lane15;
        const float bv = bo[col];
#pragma unroll
        for (int mi = 0; mi < 4; mi++) {
            const int row = bm + mi * 16 + quad * 4;
#pragma unroll
            for (int r = 0; r < 4; r++)
                out[(size_t)(row + r) * SIZE + col] = acc[mi][ni][r] + bv;
        }
    }
}

extern "C" void kernel_launch(void* const* d_in, const int* in_sizes, int n_in,
                              void* d_out, int out_size, void* d_ws, size_t ws_size,
                              hipStream_t stream) {
    const float* q  = (const float*)d_in[0];
    const float* k  = (const float*)d_in[1];
    const float* v  = (const float*)d_in[2];
    const float* Wq = (const float*)d_in[3];
    const float* bq = (const float*)d_in[4];
    const float* Wk = (const float*)d_in[5];
    const float* bk = (const float*)d_in[6];
    const float* Wv = (const float*)d_in[7];
    const float* bv = (const float*)d_in[8];
    const float* Wo = (const float*)d_in[9];
    const float* bo = (const float*)d_in[10];
    float* out = (float*)d_out;

    // ws (bf16): Wb[4M] | qb | kb | vb | qh | kh | vt  (4.19M elems each)
    // aliases: po (8.39M) = qb+kb (dead after qkv); ctx = vb; pl = Wq slot
    bf16* Wb  = (bf16*)d_ws;
    bf16* qb  = Wb + (size_t)4 * SIZE * SIZE;
    bf16* kb  = qb + (size_t)MROWS * SIZE;
    bf16* vb  = kb + (size_t)MROWS * SIZE;
    bf16* qh  = vb + (size_t)MROWS * SIZE;
    bf16* kh  = qh + (size_t)MROWS * SIZE;
    bf16* vt  = kh + (size_t)MROWS * SIZE;
    bf16* po  = qb;
    bf16* ctx = vb;
    float* pl = (float*)Wb;

    cast_kernel<<<dim3(MROWS * SIZE / 2048, 1, 7), 256, 0, stream>>>(
        Wq, Wk, Wv, Wo, q, k, v, Wb, qb, kb, vb);
    qkv_proj_kernel<<<dim3(SIZE / 128, MROWS / 128, 3), 256, 0, stream>>>(
        qb, kb, vb, Wb, bq, bk, bv, qh, kh, vt);
    attn_kernel<<<dim3(NQT * 2, NH, BB), 256, 0, stream>>>(qh, kh, vt, po, pl);
    combine_kernel<<<dim3(NQT, NH, BB), 256, 0, stream>>>(po, pl, ctx);
    out_proj_kernel<<<dim3(SIZE / 128, MROWS / 64, 1), 256, 0, stream>>>(
        ctx, Wb + (size_t)3 * SIZE * SIZE, bo, out);
}

// Round 2
// 261.428 us; speedup vs baseline: 1.0975x; 1.0975x over previous
//
#include <hip/hip_runtime.h>
#include <hip/hip_bf16.h>

#define SIZE 1024
#define NH 16
#define HD 64
#define BB 2
#define SS 2048
#define MROWS (BB * SS)  // 4096
#define QT 256           // attn q-tile (64 rows per wave)
#define NQT (SS / QT)    // 8 q-tiles per (b,h)
#define NKT ((SS / 2) / 64)  // 16 k-tiles per S-half

using bf16 = __hip_bfloat16;
using frag16 = __attribute__((ext_vector_type(8))) short;   // 8 bf16 (4 VGPRs)
using f32x4 = __attribute__((ext_vector_type(4))) float;    // 4 fp32 acc
typedef unsigned int u32;

// async global->LDS, 16B per lane; lds dest = wave-uniform base + lane*16 (m97/m104)
__device__ __forceinline__ void glds16(const bf16* g, bf16* l) {
    __builtin_amdgcn_global_load_lds(
        (const __attribute__((address_space(1))) u32*)g,
        (__attribute__((address_space(3))) u32*)l, 16, 0, 0);
}

__device__ __forceinline__ void cvt_store8(bf16* dst, const float* src) {
    float4 a = *(const float4*)src;
    float4 b = *(const float4*)(src + 4);
    bf16 t[8];
    t[0] = __float2bfloat16(a.x); t[1] = __float2bfloat16(a.y);
    t[2] = __float2bfloat16(a.z); t[3] = __float2bfloat16(a.w);
    t[4] = __float2bfloat16(b.x); t[5] = __float2bfloat16(b.y);
    t[6] = __float2bfloat16(b.z); t[7] = __float2bfloat16(b.w);
    *(uint4*)dst = *(const uint4*)t;
}

// ---------------------------------------------------------------------------
// fp32 -> bf16 cast: z = 0..3 weights, z = 4..6 activations
// ---------------------------------------------------------------------------
__global__ __launch_bounds__(256) void cast_kernel(
    const float* __restrict__ Wq, const float* __restrict__ Wk,
    const float* __restrict__ Wv, const float* __restrict__ Wo,
    const float* __restrict__ q, const float* __restrict__ k,
    const float* __restrict__ v,
    bf16* __restrict__ Wb, bf16* __restrict__ qb,
    bf16* __restrict__ kb, bf16* __restrict__ vb)
{
    const int z = blockIdx.z;
    const float* s; bf16* d; int n;
    switch (z) {
        case 0: s = Wq; d = Wb;                   n = SIZE * SIZE;  break;
        case 1: s = Wk; d = Wb + SIZE * SIZE;     n = SIZE * SIZE;  break;
        case 2: s = Wv; d = Wb + 2 * SIZE * SIZE; n = SIZE * SIZE;  break;
        case 3: s = Wo; d = Wb + 3 * SIZE * SIZE; n = SIZE * SIZE;  break;
        case 4: s = q;  d = qb;                   n = MROWS * SIZE; break;
        case 5: s = k;  d = kb;                   n = MROWS * SIZE; break;
        default: s = v; d = vb;                   n = MROWS * SIZE; break;
    }
    const int i = (blockIdx.x * 256 + threadIdx.x) * 8;
    if (i < n) cvt_store8(d + i, s + i);
}

// ---------------------------------------------------------------------------
// m97-style qkv GEMM (R5-proven): 128x128 tile, BK=32, glds16 staging, bf16.
// vt_mode: epilogue transposes via LDS and writes vt[b][h][d][s] coalesced.
// ---------------------------------------------------------------------------
__device__ __forceinline__ void gemm_body(
    const bf16* __restrict__ X, const bf16* __restrict__ W,
    const float* __restrict__ bias, bf16* __restrict__ Y, float scale, bool vt_mode)
{
    __shared__ __align__(16) bf16 smem[8704];   // As[4096] | Bs[4096]; reused as tr[64][136]
    bf16* As = smem;
    bf16* Bs = smem + 4096;

    const int tid = threadIdx.x;
    const int wave = tid >> 6;
    const int lane = tid & 63;
    const int lane15 = lane & 15;
    const int quad = lane >> 4;
    const int bm = blockIdx.y * 128;
    const int bn = blockIdx.x * 128;
    const int wm = (wave & 1) * 64;
    const int wn = (wave >> 1) * 64;

    f32x4 acc[4][4];
#pragma unroll
    for (int i = 0; i < 4; i++)
#pragma unroll
        for (int j = 0; j < 4; j++)
            acc[i][j] = (f32x4){0.f, 0.f, 0.f, 0.f};

    const int srow = lane >> 2;        // 0..15 within chunk
    const int scol = (lane & 3) * 8;   // 0/8/16/24

    for (int kt = 0; kt < SIZE / 32; kt++) {
        const int k0 = kt * 32;
        __syncthreads();
#pragma unroll
        for (int n = 0; n < 2; n++) {
            const int c = wave * 2 + n;   // chunk 0..7, 16 rows each
            glds16(X + (size_t)(bm + c * 16 + srow) * SIZE + k0 + scol, As + c * 512);
            glds16(W + (size_t)(bn + c * 16 + srow) * SIZE + k0 + scol, Bs + c * 512);
        }
        __syncthreads();

        frag16 a[4], b[4];
#pragma unroll
        for (int mi = 0; mi < 4; mi++)
            a[mi] = *(const frag16*)(As + (wm + mi * 16 + lane15) * 32 + quad * 8);
#pragma unroll
        for (int ni = 0; ni < 4; ni++)
            b[ni] = *(const frag16*)(Bs + (wn + ni * 16 + lane15) * 32 + quad * 8);
#pragma unroll
        for (int mi = 0; mi < 4; mi++)
#pragma unroll
            for (int ni = 0; ni < 4; ni++)
                acc[mi][ni] = __builtin_amdgcn_mfma_f32_16x16x32_bf16(
                    a[mi], b[ni], acc[mi][ni], 0, 0, 0);
    }

    if (!vt_mode) {
        // C/D layout col=lane&15, row=quad*4+reg (m89/m91)
#pragma unroll
        for (int ni = 0; ni < 4; ni++) {
            const int col = bn + wn + ni * 16 + lane15;
            const float bv = bias[col];
#pragma unroll
            for (int mi = 0; mi < 4; mi++) {
                const int row = bm + wm + mi * 16 + quad * 4;
#pragma unroll
                for (int r = 0; r < 4; r++)
                    Y[(size_t)(row + r) * SIZE + col] =
                        __float2bfloat16((acc[mi][ni][r] + bv) * scale);
            }
        }
    } else {
        // transpose epilogue -> vt[b][h][d][s], coalesced 16B stores
        bf16* tr = smem;                   // [64][136]
        const int bloc = bm >> 11;
        const int s0g = bm & (SS - 1);
#pragma unroll
        for (int p = 0; p < 2; p++) {
            __syncthreads();
            if ((wave >> 1) == p) {
#pragma unroll
                for (int ni = 0; ni < 4; ni++) {
                    const int colp = ni * 16 + lane15;
                    const float bv = bias[bn + p * 64 + colp];
#pragma unroll
                    for (int mi = 0; mi < 4; mi++) {
                        const int row = wm + mi * 16 + quad * 4;
#pragma unroll
                        for (int r = 0; r < 4; r++)
                            tr[colp * 136 + row + r] =
                                __float2bfloat16(acc[mi][ni][r] + bv);
                    }
                }
            }
            __syncthreads();
            const int colp = tid >> 2;
            const int gcol = bn + p * 64 + colp;
            const int hh = gcol >> 6, dd = gcol & (HD - 1);
            bf16* dst = (bf16*)Y + ((size_t)(bloc * NH + hh) * HD + dd) * SS
                        + s0g + (tid & 3) * 32;
            const bf16* src = tr + colp * 136 + (tid & 3) * 32;
#pragma unroll
            for (int j = 0; j < 4; j++)
                *(uint4*)(dst + j * 8) = *(const uint4*)(src + j * 8);
        }
    }
}

__global__ __launch_bounds__(256) void qkv_proj_kernel(
    const bf16* __restrict__ qb, const bf16* __restrict__ kb, const bf16* __restrict__ vb,
    const bf16* __restrict__ Wb,
    const float* __restrict__ bq, const float* __restrict__ bk, const float* __restrict__ bv,
    bf16* __restrict__ qh, bf16* __restrict__ kh, bf16* __restrict__ vt)
{
    const bf16 *X, *W; const float* bi; bf16* Y; float sc; bool vm;
    if (blockIdx.z == 0)      { X = qb; W = Wb;                   bi = bq; Y = qh; sc = 0.125f; vm = false; }
    else if (blockIdx.z == 1) { X = kb; W = Wb + SIZE * SIZE;     bi = bk; Y = kh; sc = 1.0f;   vm = false; }
    else                      { X = vb; W = Wb + 2 * SIZE * SIZE; bi = bv; Y = vt; sc = 1.0f;   vm = true;  }
    gemm_body(X, W, bi, Y, sc, vm);
}

// ---------------------------------------------------------------------------
// Flash attention, split-S. LDS-pipe is the bottleneck (R0/R1 post-mortem):
// kf/Vs/staging LDS reads are per-wave-per-kt regardless of q-rows owned,
// so each wave now owns 64 q-rows (m=0..3) instead of 32 -> LDS cycles per
// unit work drop 336->216. All MFMAs stay 16x16x32 (K=16 PV regressed in R1).
// QT=256, grid 512 = 2 blocks/CU (LDS 55.3KB), 8 waves/CU.
// S^T trick: S^T = K Q^T so C-layout regs are 4 consecutive keys at fixed q
// -> packed 8B Ps store; fixed-offset softmax; l = P @ ones via MFMA.
// ---------------------------------------------------------------------------
__global__ __launch_bounds__(256) void attn_kernel(
    const bf16* __restrict__ qh, const bf16* __restrict__ kh,
    const bf16* __restrict__ vt, bf16* __restrict__ po, float* __restrict__ pl)
{
    __shared__ __align__(16) bf16 Ks[64][72];
    __shared__ __align__(16) bf16 Vs[64][72];
    __shared__ __align__(16) bf16 Ps[4][64][72];

    const int tid = threadIdx.x;
    const int wave = tid >> 6;
    const int lane = tid & 63;
    const int lane15 = lane & 15;
    const int quad = lane >> 4;

    const int b = blockIdx.z, h = blockIdx.y;
    const int qt = blockIdx.x >> 1;
    const int sh = blockIdx.x & 1;
    const int q0 = qt * QT;

    const size_t baseq = (size_t)b * SS * SIZE + (size_t)h * HD;
    const size_t basev = (size_t)(b * NH + h) * HD * SS;
    const float LOG2E = 1.44269504088896340736f;
    const float OFF = 12.0f * LOG2E;

    frag16 aq[4][2];
#pragma unroll
    for (int m = 0; m < 4; m++) {
        const int qrow = q0 + wave * 64 + m * 16 + lane15;
        const bf16* qp = qh + baseq + (size_t)qrow * SIZE + quad * 8;
        aq[m][0] = *(const frag16*)(qp);
        aq[m][1] = *(const frag16*)(qp + 32);
    }

    frag16 bones;
#pragma unroll
    for (int e = 0; e < 8; e++) bones[e] = (short)0x3F80;   // bf16 1.0

    f32x4 ofrag[4][4], l_frag[4];
#pragma unroll
    for (int m = 0; m < 4; m++) {
        l_frag[m] = (f32x4){0.f, 0.f, 0.f, 0.f};
#pragma unroll
        for (int dt = 0; dt < 4; dt++) ofrag[m][dt] = (f32x4){0.f, 0.f, 0.f, 0.f};
    }

    const int sr = tid >> 3;          // 0..31
    const int sc = (tid & 7) * 8;

    for (int kt = 0; kt < NKT; kt++) {
        const int s0 = sh * (SS / 2) + kt * 64;
        __syncthreads();
        *(uint4*)&Ks[sr][sc]      = *(const uint4*)(kh + baseq + (size_t)(s0 + sr) * SIZE + sc);
        *(uint4*)&Ks[sr + 32][sc] = *(const uint4*)(kh + baseq + (size_t)(s0 + sr + 32) * SIZE + sc);
        *(uint4*)&Vs[sr][sc]      = *(const uint4*)(vt + basev + (size_t)sr * SS + s0 + sc);
        *(uint4*)&Vs[sr + 32][sc] = *(const uint4*)(vt + basev + (size_t)(sr + 32) * SS + s0 + sc);
        __syncthreads();

        // ---- S^T = K Q^T, softmax, packed P store ----
        frag16 kf[4][2];
#pragma unroll
        for (int nt = 0; nt < 4; nt++) {
            kf[nt][0] = *(const frag16*)&Ks[nt * 16 + lane15][quad * 8];
            kf[nt][1] = *(const frag16*)&Ks[nt * 16 + lane15][32 + quad * 8];
        }
#pragma unroll
        for (int m = 0; m < 4; m++) {
#pragma unroll
            for (int nt = 0; nt < 4; nt++) {
                f32x4 c = (f32x4){0.f, 0.f, 0.f, 0.f};
                c = __builtin_amdgcn_mfma_f32_16x16x32_bf16(kf[nt][0], aq[m][0], c, 0, 0, 0);
                c = __builtin_amdgcn_mfma_f32_16x16x32_bf16(kf[nt][1], aq[m][1], c, 0, 0, 0);
                // c[r] = S[q = m*16+lane15][key = nt*16 + quad*4 + r]
                bf16 p4[4];
#pragma unroll
                for (int r = 0; r < 4; r++)
                    p4[r] = __float2bfloat16(exp2f(c[r] * LOG2E - OFF));
                *(uint2*)&Ps[wave][m * 16 + lane15][nt * 16 + quad * 4] = *(const uint2*)p4;
            }
        }
        __builtin_amdgcn_wave_barrier();   // Ps wave-private; DS in-order per wave

        frag16 ap[4][2];
#pragma unroll
        for (int m = 0; m < 4; m++)
#pragma unroll
            for (int c2 = 0; c2 < 2; c2++)
                ap[m][c2] = *(const frag16*)&Ps[wave][m * 16 + lane15][c2 * 32 + quad * 8];

        // ---- l += P @ 1 ----
#pragma unroll
        for (int m = 0; m < 4; m++)
#pragma unroll
            for (int c2 = 0; c2 < 2; c2++)
                l_frag[m] = __builtin_amdgcn_mfma_f32_16x16x32_bf16(
                    ap[m][c2], bones, l_frag[m], 0, 0, 0);

        // ---- O += P V ----
#pragma unroll
        for (int dt = 0; dt < 4; dt++) {
            frag16 bv0 = *(const frag16*)&Vs[dt * 16 + lane15][quad * 8];
            frag16 bv1 = *(const frag16*)&Vs[dt * 16 + lane15][32 + quad * 8];
#pragma unroll
            for (int m = 0; m < 4; m++) {
                ofrag[m][dt] = __builtin_amdgcn_mfma_f32_16x16x32_bf16(ap[m][0], bv0, ofrag[m][dt], 0, 0, 0);
                ofrag[m][dt] = __builtin_amdgcn_mfma_f32_16x16x32_bf16(ap[m][1], bv1, ofrag[m][dt], 0, 0, 0);
            }
        }
    }

    // ---- partial outputs (un-normalized O + row sums) ----
    const int pb = ((b * NH + h) * NQT + qt) * 2 + sh;
    if (lane15 == 0) {
        float* plp = pl + (size_t)pb * QT;
#pragma unroll
        for (int m = 0; m < 4; m++)
#pragma unroll
            for (int r = 0; r < 4; r++)
                plp[wave * 64 + m * 16 + quad * 4 + r] = l_frag[m][r];
    }
    bf16* pop = po + (size_t)pb * QT * HD;
#pragma unroll
    for (int m = 0; m < 4; m++)
#pragma unroll
        for (int dt = 0; dt < 4; dt++)
#pragma unroll
            for (int r = 0; r < 4; r++)
                pop[(size_t)(wave * 64 + m * 16 + quad * 4 + r) * HD + dt * 16 + lane15] =
                    __float2bfloat16(ofrag[m][dt][r]);
}

// ---------------------------------------------------------------------------
// Combine the two S-halves: ctx = (po0 + po1) / (l0 + l1), write [b][s][h*64+d]
// Grid keeps 128-row tiles; maps into the QT=256 attn partial layout.
// ---------------------------------------------------------------------------
__global__ __launch_bounds__(256) void combine_kernel(
    const bf16* __restrict__ po, const float* __restrict__ pl, bf16* __restrict__ ctx)
{
    const int b = blockIdx.z, h = blockIdx.y, qt = blockIdx.x;   // qt: 128-row tile 0..15
    const int t = (b * NH + h) * NQT + (qt >> 1);
    const int rbase = (qt & 1) * 128;
    const bf16* p0 = po + (size_t)(t * 2 + 0) * QT * HD;
    const bf16* p1 = po + (size_t)(t * 2 + 1) * QT * HD;
    const int qr = threadIdx.x >> 1;
    const int dh = (threadIdx.x & 1) * 32;
    const int row = rbase + qr;
    const float l = pl[(size_t)(t * 2) * QT + row] + pl[(size_t)(t * 2 + 1) * QT + row];
    const float inv = 1.0f / fmaxf(l, 1e-30f);
    bf16* dst = ctx + ((size_t)b * SS + qt * 128 + qr) * SIZE + h * HD + dh;
    const bf16* s0p = p0 + row * HD + dh;
    const bf16* s1p = p1 + row * HD + dh;
#pragma unroll
    for (int j = 0; j < 32; j += 8) {
        uint4 u0 = *(const uint4*)(s0p + j);
        uint4 u1 = *(const uint4*)(s1p + j);
        const bf16* a = (const bf16*)&u0;
        const bf16* bt = (const bf16*)&u1;
        bf16 o[8];
#pragma unroll
        for (int e = 0; e < 8; e++)
            o[e] = __float2bfloat16((__bfloat162float(a[e]) + __bfloat162float(bt[e])) * inv);
        *(uint4*)(dst + j) = *(const uint4*)o;
    }
}

// ---------------------------------------------------------------------------
// Output projection: BM=64 x BN=128 -> 512 blocks = 2/CU. bf16 glds16 staging
// both operands. fp32 out.
// ---------------------------------------------------------------------------
__global__ __launch_bounds__(256) void out_proj_kernel(
    const bf16* __restrict__ ctx, const bf16* __restrict__ Wob,
    const float* __restrict__ bo, float* __restrict__ out)
{
    __shared__ __align__(16) bf16 As[64 * 32];
    __shared__ __align__(16) bf16 Bs[128 * 32];

    const int tid = threadIdx.x;
    const int wave = tid >> 6;
    const int lane = tid & 63;
    const int lane15 = lane & 15;
    const int quad = lane >> 4;
    const int bm = blockIdx.y * 64;
    const int bn = blockIdx.x * 128;
    const int wn = wave * 32;

    f32x4 acc[4][2];
#pragma unroll
    for (int i = 0; i < 4; i++)
#pragma unroll
        for (int j = 0; j < 2; j++)
            acc[i][j] = (f32x4){0.f, 0.f, 0.f, 0.f};

    const int srow = lane >> 2;        // 0..15 within chunk
    const int scol = (lane & 3) * 8;

    for (int kt = 0; kt < SIZE / 32; kt++) {
        const int k0 = kt * 32;
        __syncthreads();
        glds16(ctx + (size_t)(bm + wave * 16 + srow) * SIZE + k0 + scol, As + wave * 512);
#pragma unroll
        for (int n = 0; n < 2; n++) {
            const int c = wave * 2 + n;
            glds16(Wob + (size_t)(bn + c * 16 + srow) * SIZE + k0 + scol, Bs + c * 512);
        }
        __syncthreads();

        frag16 a[4], b[2];
#pragma unroll
        for (int mi = 0; mi < 4; mi++)
            a[mi] = *(const frag16*)(As + (mi * 16 + lane15) * 32 + quad * 8);
#pragma unroll
        for (int ni = 0; ni < 2; ni++)
            b[ni] = *(const frag16*)(Bs + (wn + ni * 16 + lane15) * 32 + quad * 8);
#pragma unroll
        for (int mi = 0; mi < 4; mi++)
#pragma unroll
            for (int ni = 0; ni < 2; ni++)
                acc[mi][ni] = __builtin_amdgcn_mfma_f32_16x16x32_bf16(
                    a[mi], b[ni], acc[mi][ni], 0, 0, 0);
    }

#pragma unroll
    for (int ni = 0; ni < 2; ni++) {
        const int col = bn + wn + ni * 16 + lane15;
        const float bv = bo[col];
#pragma unroll
        for (int mi = 0; mi < 4; mi++) {
            const int row = bm + mi * 16 + quad * 4;
#pragma unroll
            for (int r = 0; r < 4; r++)
                out[(size_t)(row + r) * SIZE + col] = acc[mi][ni][r] + bv;
        }
    }
}

extern "C" void kernel_launch(void* const* d_in, const int* in_sizes, int n_in,
                              void* d_out, int out_size, void* d_ws, size_t ws_size,
                              hipStream_t stream) {
    const float* q  = (const float*)d_in[0];
    const float* k  = (const float*)d_in[1];
    const float* v  = (const float*)d_in[2];
    const float* Wq = (const float*)d_in[3];
    const float* bq = (const float*)d_in[4];
    const float* Wk = (const float*)d_in[5];
    const float* bk = (const float*)d_in[6];
    const float* Wv = (const float*)d_in[7];
    const float* bv = (const float*)d_in[8];
    const float* Wo = (const float*)d_in[9];
    const float* bo = (const float*)d_in[10];
    float* out = (float*)d_out;

    // ws (bf16): Wb[4M] | qb | kb | vb | qh | kh | vt  (4.19M elems each)
    // aliases: po (8.39M) = qb+kb (dead after qkv); ctx = vb; pl = Wq slot
    bf16* Wb  = (bf16*)d_ws;
    bf16* qb  = Wb + (size_t)4 * SIZE * SIZE;
    bf16* kb  = qb + (size_t)MROWS * SIZE;
    bf16* vb  = kb + (size_t)MROWS * SIZE;
    bf16* qh  = vb + (size_t)MROWS * SIZE;
    bf16* kh  = qh + (size_t)MROWS * SIZE;
    bf16* vt  = kh + (size_t)MROWS * SIZE;
    bf16* po  = qb;
    bf16* ctx = vb;
    float* pl = (float*)Wb;

    cast_kernel<<<dim3(MROWS * SIZE / 2048, 1, 7), 256, 0, stream>>>(
        Wq, Wk, Wv, Wo, q, k, v, Wb, qb, kb, vb);
    qkv_proj_kernel<<<dim3(SIZE / 128, MROWS / 128, 3), 256, 0, stream>>>(
        qb, kb, vb, Wb, bq, bk, bv, qh, kh, vt);
    attn_kernel<<<dim3(NQT * 2, NH, BB), 256, 0, stream>>>(qh, kh, vt, po, pl);
    combine_kernel<<<dim3(SS / 128, NH, BB), 256, 0, stream>>>(po, pl, ctx);
    out_proj_kernel<<<dim3(SIZE / 128, MROWS / 64, 1), 256, 0, stream>>>(
        ctx, Wb + (size_t)3 * SIZE * SIZE, bo, out);
}

// Round 3
// 252.877 us; speedup vs baseline: 1.1347x; 1.0338x over previous
//
#include <hip/hip_runtime.h>
#include <hip/hip_bf16.h>

#define SIZE 1024
#define NH 16
#define HD 64
#define BB 2
#define SS 2048
#define MROWS (BB * SS)  // 4096
#define QT 256           // attn q-tile (64 rows per wave)
#define NQT (SS / QT)    // 8 q-tiles per (b,h)
#define NKT ((SS / 2) / 64)  // 16 k-tiles per S-half

using bf16 = __hip_bfloat16;
using frag16 = __attribute__((ext_vector_type(8))) short;   // 8 bf16 (4 VGPRs)
using f32x4 = __attribute__((ext_vector_type(4))) float;    // 4 fp32 acc
typedef unsigned int u32;

// async global->LDS, 16B per lane; lds dest = wave-uniform base + lane*16 (m97/m104)
__device__ __forceinline__ void glds16(const bf16* g, bf16* l) {
    __builtin_amdgcn_global_load_lds(
        (const __attribute__((address_space(1))) u32*)g,
        (__attribute__((address_space(3))) u32*)l, 16, 0, 0);
}

__device__ __forceinline__ void cvt_store8(bf16* dst, const float* src) {
    float4 a = *(const float4*)src;
    float4 b = *(const float4*)(src + 4);
    bf16 t[8];
    t[0] = __float2bfloat16(a.x); t[1] = __float2bfloat16(a.y);
    t[2] = __float2bfloat16(a.z); t[3] = __float2bfloat16(a.w);
    t[4] = __float2bfloat16(b.x); t[5] = __float2bfloat16(b.y);
    t[6] = __float2bfloat16(b.z); t[7] = __float2bfloat16(b.w);
    *(uint4*)dst = *(const uint4*)t;
}

// ---------------------------------------------------------------------------
// fp32 -> bf16 cast: z = 0..3 weights, z = 4..6 activations
// ---------------------------------------------------------------------------
__global__ __launch_bounds__(256) void cast_kernel(
    const float* __restrict__ Wq, const float* __restrict__ Wk,
    const float* __restrict__ Wv, const float* __restrict__ Wo,
    const float* __restrict__ q, const float* __restrict__ k,
    const float* __restrict__ v,
    bf16* __restrict__ Wb, bf16* __restrict__ qb,
    bf16* __restrict__ kb, bf16* __restrict__ vb)
{
    const int z = blockIdx.z;
    const float* s; bf16* d; int n;
    switch (z) {
        case 0: s = Wq; d = Wb;                   n = SIZE * SIZE;  break;
        case 1: s = Wk; d = Wb + SIZE * SIZE;     n = SIZE * SIZE;  break;
        case 2: s = Wv; d = Wb + 2 * SIZE * SIZE; n = SIZE * SIZE;  break;
        case 3: s = Wo; d = Wb + 3 * SIZE * SIZE; n = SIZE * SIZE;  break;
        case 4: s = q;  d = qb;                   n = MROWS * SIZE; break;
        case 5: s = k;  d = kb;                   n = MROWS * SIZE; break;
        default: s = v; d = vb;                   n = MROWS * SIZE; break;
    }
    const int i = (blockIdx.x * 256 + threadIdx.x) * 8;
    if (i < n) cvt_store8(d + i, s + i);
}

// ---------------------------------------------------------------------------
// m97-style qkv GEMM: 128x128 tile, BK=32, glds16 staging, bf16.
// vt_mode: epilogue transposes via LDS and writes vt[b][h][d][s] coalesced.
// ---------------------------------------------------------------------------
__device__ __forceinline__ void gemm_body(
    const bf16* __restrict__ X, const bf16* __restrict__ W,
    const float* __restrict__ bias, bf16* __restrict__ Y, float scale, bool vt_mode)
{
    __shared__ __align__(16) bf16 smem[8704];   // As[4096] | Bs[4096]; reused as tr[64][136]
    bf16* As = smem;
    bf16* Bs = smem + 4096;

    const int tid = threadIdx.x;
    const int wave = tid >> 6;
    const int lane = tid & 63;
    const int lane15 = lane & 15;
    const int quad = lane >> 4;
    const int bm = blockIdx.y * 128;
    const int bn = blockIdx.x * 128;
    const int wm = (wave & 1) * 64;
    const int wn = (wave >> 1) * 64;

    f32x4 acc[4][4];
#pragma unroll
    for (int i = 0; i < 4; i++)
#pragma unroll
        for (int j = 0; j < 4; j++)
            acc[i][j] = (f32x4){0.f, 0.f, 0.f, 0.f};

    const int srow = lane >> 2;        // 0..15 within chunk
    const int scol = (lane & 3) * 8;   // 0/8/16/24

    for (int kt = 0; kt < SIZE / 32; kt++) {
        const int k0 = kt * 32;
        __syncthreads();
#pragma unroll
        for (int n = 0; n < 2; n++) {
            const int c = wave * 2 + n;   // chunk 0..7, 16 rows each
            glds16(X + (size_t)(bm + c * 16 + srow) * SIZE + k0 + scol, As + c * 512);
            glds16(W + (size_t)(bn + c * 16 + srow) * SIZE + k0 + scol, Bs + c * 512);
        }
        __syncthreads();

        frag16 a[4], b[4];
#pragma unroll
        for (int mi = 0; mi < 4; mi++)
            a[mi] = *(const frag16*)(As + (wm + mi * 16 + lane15) * 32 + quad * 8);
#pragma unroll
        for (int ni = 0; ni < 4; ni++)
            b[ni] = *(const frag16*)(Bs + (wn + ni * 16 + lane15) * 32 + quad * 8);
#pragma unroll
        for (int mi = 0; mi < 4; mi++)
#pragma unroll
            for (int ni = 0; ni < 4; ni++)
                acc[mi][ni] = __builtin_amdgcn_mfma_f32_16x16x32_bf16(
                    a[mi], b[ni], acc[mi][ni], 0, 0, 0);
    }

    if (!vt_mode) {
        // C/D layout col=lane&15, row=quad*4+reg (m89/m91)
#pragma unroll
        for (int ni = 0; ni < 4; ni++) {
            const int col = bn + wn + ni * 16 + lane15;
            const float bv = bias[col];
#pragma unroll
            for (int mi = 0; mi < 4; mi++) {
                const int row = bm + wm + mi * 16 + quad * 4;
#pragma unroll
                for (int r = 0; r < 4; r++)
                    Y[(size_t)(row + r) * SIZE + col] =
                        __float2bfloat16((acc[mi][ni][r] + bv) * scale);
            }
        }
    } else {
        // transpose epilogue -> vt[b][h][d][s], coalesced 16B stores
        bf16* tr = smem;                   // [64][136]
        const int bloc = bm >> 11;
        const int s0g = bm & (SS - 1);
#pragma unroll
        for (int p = 0; p < 2; p++) {
            __syncthreads();
            if ((wave >> 1) == p) {
#pragma unroll
                for (int ni = 0; ni < 4; ni++) {
                    const int colp = ni * 16 + lane15;
                    const float bv = bias[bn + p * 64 + colp];
#pragma unroll
                    for (int mi = 0; mi < 4; mi++) {
                        const int row = wm + mi * 16 + quad * 4;
#pragma unroll
                        for (int r = 0; r < 4; r++)
                            tr[colp * 136 + row + r] =
                                __float2bfloat16(acc[mi][ni][r] + bv);
                    }
                }
            }
            __syncthreads();
            const int colp = tid >> 2;
            const int gcol = bn + p * 64 + colp;
            const int hh = gcol >> 6, dd = gcol & (HD - 1);
            bf16* dst = (bf16*)Y + ((size_t)(bloc * NH + hh) * HD + dd) * SS
                        + s0g + (tid & 3) * 32;
            const bf16* src = tr + colp * 136 + (tid & 3) * 32;
#pragma unroll
            for (int j = 0; j < 4; j++)
                *(uint4*)(dst + j * 8) = *(const uint4*)(src + j * 8);
        }
    }
}

__global__ __launch_bounds__(256) void qkv_proj_kernel(
    const bf16* __restrict__ qb, const bf16* __restrict__ kb, const bf16* __restrict__ vb,
    const bf16* __restrict__ Wb,
    const float* __restrict__ bq, const float* __restrict__ bk, const float* __restrict__ bv,
    bf16* __restrict__ qh, bf16* __restrict__ kh, bf16* __restrict__ vt)
{
    const bf16 *X, *W; const float* bi; bf16* Y; float sc; bool vm;
    if (blockIdx.z == 0)      { X = qb; W = Wb;                   bi = bq; Y = qh; sc = 0.125f; vm = false; }
    else if (blockIdx.z == 1) { X = kb; W = Wb + SIZE * SIZE;     bi = bk; Y = kh; sc = 1.0f;   vm = false; }
    else                      { X = vb; W = Wb + 2 * SIZE * SIZE; bi = bv; Y = vt; sc = 1.0f;   vm = true;  }
    gemm_body(X, W, bi, Y, sc, vm);
}

// ---------------------------------------------------------------------------
// Flash attention, split-S, QT=256 (64 q-rows/wave), DOUBLE-BUFFERED K/V.
// R0/R2 showed time pinned at ~78us across big LDS/occupancy changes ->
// bottleneck = serial per-kt staging (exposed global latency + 2 barriers,
// phase-locked across co-resident blocks). Fix (T14 async-STAGE + dbuf):
// issue kt+1 global loads BEFORE compute(kt) (sched_barrier-pinned), commit
// regs->LDS after compute, ONE barrier per kt. Latency hides under ~3K-cycle
// compute phase. setprio(1) around the pure-MFMA PV cluster (m191).
// LDS 73.7KB -> 2 blocks/CU, grid 512 = fully resident.
// ---------------------------------------------------------------------------
__global__ __launch_bounds__(256) void attn_kernel(
    const bf16* __restrict__ qh, const bf16* __restrict__ kh,
    const bf16* __restrict__ vt, bf16* __restrict__ po, float* __restrict__ pl)
{
    __shared__ __align__(16) bf16 Ks[2][64][72];
    __shared__ __align__(16) bf16 Vs[2][64][72];
    __shared__ __align__(16) bf16 Ps[4][64][72];

    const int tid = threadIdx.x;
    const int wave = tid >> 6;
    const int lane = tid & 63;
    const int lane15 = lane & 15;
    const int quad = lane >> 4;

    const int b = blockIdx.z, h = blockIdx.y;
    const int qt = blockIdx.x >> 1;
    const int sh = blockIdx.x & 1;
    const int q0 = qt * QT;

    const size_t baseq = (size_t)b * SS * SIZE + (size_t)h * HD;
    const size_t basev = (size_t)(b * NH + h) * HD * SS;
    const float LOG2E = 1.44269504088896340736f;
    const float OFF = 12.0f * LOG2E;

    frag16 aq[4][2];
#pragma unroll
    for (int m = 0; m < 4; m++) {
        const int qrow = q0 + wave * 64 + m * 16 + lane15;
        const bf16* qp = qh + baseq + (size_t)qrow * SIZE + quad * 8;
        aq[m][0] = *(const frag16*)(qp);
        aq[m][1] = *(const frag16*)(qp + 32);
    }

    frag16 bones;
#pragma unroll
    for (int e = 0; e < 8; e++) bones[e] = (short)0x3F80;   // bf16 1.0

    f32x4 ofrag[4][4], l_frag[4];
#pragma unroll
    for (int m = 0; m < 4; m++) {
        l_frag[m] = (f32x4){0.f, 0.f, 0.f, 0.f};
#pragma unroll
        for (int dt = 0; dt < 4; dt++) ofrag[m][dt] = (f32x4){0.f, 0.f, 0.f, 0.f};
    }

    const int sr = tid >> 3;          // 0..31
    const int sc = (tid & 7) * 8;

    // staging registers (tile in flight)
    uint4 rk0, rk1, rv0, rv1;

#define ISSUE(KT)                                                              \
    {                                                                          \
        const int s0_ = sh * (SS / 2) + (KT) * 64;                             \
        rk0 = *(const uint4*)(kh + baseq + (size_t)(s0_ + sr) * SIZE + sc);    \
        rk1 = *(const uint4*)(kh + baseq + (size_t)(s0_ + sr + 32) * SIZE + sc);\
        rv0 = *(const uint4*)(vt + basev + (size_t)sr * SS + s0_ + sc);        \
        rv1 = *(const uint4*)(vt + basev + (size_t)(sr + 32) * SS + s0_ + sc); \
    }
#define COMMIT(BUF)                                                            \
    {                                                                          \
        *(uint4*)&Ks[BUF][sr][sc] = rk0; *(uint4*)&Ks[BUF][sr + 32][sc] = rk1; \
        *(uint4*)&Vs[BUF][sr][sc] = rv0; *(uint4*)&Vs[BUF][sr + 32][sc] = rv1; \
    }

    // prologue: tile 0 (latency exposed once)
    ISSUE(0); COMMIT(0);
    __syncthreads();

    for (int kt = 0; kt < NKT; kt++) {
        const int buf = kt & 1;
        if (kt + 1 < NKT) ISSUE(kt + 1);          // prefetch in flight
        __builtin_amdgcn_sched_barrier(0);        // pin loads before compute

        // ---- S^T = K Q^T, softmax, packed P store ----
        frag16 kf[4][2];
#pragma unroll
        for (int nt = 0; nt < 4; nt++) {
            kf[nt][0] = *(const frag16*)&Ks[buf][nt * 16 + lane15][quad * 8];
            kf[nt][1] = *(const frag16*)&Ks[buf][nt * 16 + lane15][32 + quad * 8];
        }
#pragma unroll
        for (int m = 0; m < 4; m++) {
#pragma unroll
            for (int nt = 0; nt < 4; nt++) {
                f32x4 c = (f32x4){0.f, 0.f, 0.f, 0.f};
                c = __builtin_amdgcn_mfma_f32_16x16x32_bf16(kf[nt][0], aq[m][0], c, 0, 0, 0);
                c = __builtin_amdgcn_mfma_f32_16x16x32_bf16(kf[nt][1], aq[m][1], c, 0, 0, 0);
                // c[r] = S[q = m*16+lane15][key = nt*16 + quad*4 + r]
                bf16 p4[4];
#pragma unroll
                for (int r = 0; r < 4; r++)
                    p4[r] = __float2bfloat16(exp2f(c[r] * LOG2E - OFF));
                *(uint2*)&Ps[wave][m * 16 + lane15][nt * 16 + quad * 4] = *(const uint2*)p4;
            }
        }
        __builtin_amdgcn_wave_barrier();   // Ps wave-private; DS in-order per wave

        frag16 ap[4][2];
#pragma unroll
        for (int m = 0; m < 4; m++)
#pragma unroll
            for (int c2 = 0; c2 < 2; c2++)
                ap[m][c2] = *(const frag16*)&Ps[wave][m * 16 + lane15][c2 * 32 + quad * 8];

        __builtin_amdgcn_s_setprio(1);
        // ---- l += P @ 1 ----
#pragma unroll
        for (int m = 0; m < 4; m++)
#pragma unroll
            for (int c2 = 0; c2 < 2; c2++)
                l_frag[m] = __builtin_amdgcn_mfma_f32_16x16x32_bf16(
                    ap[m][c2], bones, l_frag[m], 0, 0, 0);

        // ---- O += P V ----
#pragma unroll
        for (int dt = 0; dt < 4; dt++) {
            frag16 bv0 = *(const frag16*)&Vs[buf][dt * 16 + lane15][quad * 8];
            frag16 bv1 = *(const frag16*)&Vs[buf][dt * 16 + lane15][32 + quad * 8];
#pragma unroll
            for (int m = 0; m < 4; m++) {
                ofrag[m][dt] = __builtin_amdgcn_mfma_f32_16x16x32_bf16(ap[m][0], bv0, ofrag[m][dt], 0, 0, 0);
                ofrag[m][dt] = __builtin_amdgcn_mfma_f32_16x16x32_bf16(ap[m][1], bv1, ofrag[m][dt], 0, 0, 0);
            }
        }
        __builtin_amdgcn_s_setprio(0);

        if (kt + 1 < NKT) {
            COMMIT(buf ^ 1);                      // prefetch landed by now
            __syncthreads();
        }
    }
#undef ISSUE
#undef COMMIT

    // ---- partial outputs (un-normalized O + row sums) ----
    const int pb = ((b * NH + h) * NQT + qt) * 2 + sh;
    if (lane15 == 0) {
        float* plp = pl + (size_t)pb * QT;
#pragma unroll
        for (int m = 0; m < 4; m++)
#pragma unroll
            for (int r = 0; r < 4; r++)
                plp[wave * 64 + m * 16 + quad * 4 + r] = l_frag[m][r];
    }
    bf16* pop = po + (size_t)pb * QT * HD;
#pragma unroll
    for (int m = 0; m < 4; m++)
#pragma unroll
        for (int dt = 0; dt < 4; dt++)
#pragma unroll
            for (int r = 0; r < 4; r++)
                pop[(size_t)(wave * 64 + m * 16 + quad * 4 + r) * HD + dt * 16 + lane15] =
                    __float2bfloat16(ofrag[m][dt][r]);
}

// ---------------------------------------------------------------------------
// Combine the two S-halves: ctx = (po0 + po1) / (l0 + l1), write [b][s][h*64+d]
// Grid keeps 128-row tiles; maps into the QT=256 attn partial layout.
// ---------------------------------------------------------------------------
__global__ __launch_bounds__(256) void combine_kernel(
    const bf16* __restrict__ po, const float* __restrict__ pl, bf16* __restrict__ ctx)
{
    const int b = blockIdx.z, h = blockIdx.y, qt = blockIdx.x;   // qt: 128-row tile 0..15
    const int t = (b * NH + h) * NQT + (qt >> 1);
    const int rbase = (qt & 1) * 128;
    const bf16* p0 = po + (size_t)(t * 2 + 0) * QT * HD;
    const bf16* p1 = po + (size_t)(t * 2 + 1) * QT * HD;
    const int qr = threadIdx.x >> 1;
    const int dh = (threadIdx.x & 1) * 32;
    const int row = rbase + qr;
    const float l = pl[(size_t)(t * 2) * QT + row] + pl[(size_t)(t * 2 + 1) * QT + row];
    const float inv = 1.0f / fmaxf(l, 1e-30f);
    bf16* dst = ctx + ((size_t)b * SS + qt * 128 + qr) * SIZE + h * HD + dh;
    const bf16* s0p = p0 + row * HD + dh;
    const bf16* s1p = p1 + row * HD + dh;
#pragma unroll
    for (int j = 0; j < 32; j += 8) {
        uint4 u0 = *(const uint4*)(s0p + j);
        uint4 u1 = *(const uint4*)(s1p + j);
        const bf16* a = (const bf16*)&u0;
        const bf16* bt = (const bf16*)&u1;
        bf16 o[8];
#pragma unroll
        for (int e = 0; e < 8; e++)
            o[e] = __float2bfloat16((__bfloat162float(a[e]) + __bfloat162float(bt[e])) * inv);
        *(uint4*)(dst + j) = *(const uint4*)o;
    }
}

// ---------------------------------------------------------------------------
// Output projection: BM=64 x BN=128 -> 512 blocks = 2/CU. bf16 glds16 staging
// both operands. fp32 out.
// ---------------------------------------------------------------------------
__global__ __launch_bounds__(256) void out_proj_kernel(
    const bf16* __restrict__ ctx, const bf16* __restrict__ Wob,
    const float* __restrict__ bo, float* __restrict__ out)
{
    __shared__ __align__(16) bf16 As[64 * 32];
    __shared__ __align__(16) bf16 Bs[128 * 32];

    const int tid = threadIdx.x;
    const int wave = tid >> 6;
    const int lane = tid & 63;
    const int lane15 = lane & 15;
    const int quad = lane >> 4;
    const int bm = blockIdx.y * 64;
    const int bn = blockIdx.x * 128;
    const int wn = wave * 32;

    f32x4 acc[4][2];
#pragma unroll
    for (int i = 0; i < 4; i++)
#pragma unroll
        for (int j = 0; j < 2; j++)
            acc[i][j] = (f32x4){0.f, 0.f, 0.f, 0.f};

    const int srow = lane >> 2;        // 0..15 within chunk
    const int scol = (lane & 3) * 8;

    for (int kt = 0; kt < SIZE / 32; kt++) {
        const int k0 = kt * 32;
        __syncthreads();
        glds16(ctx + (size_t)(bm + wave * 16 + srow) * SIZE + k0 + scol, As + wave * 512);
#pragma unroll
        for (int n = 0; n < 2; n++) {
            const int c = wave * 2 + n;
            glds16(Wob + (size_t)(bn + c * 16 + srow) * SIZE + k0 + scol, Bs + c * 512);
        }
        __syncthreads();

        frag16 a[4], b[2];
#pragma unroll
        for (int mi = 0; mi < 4; mi++)
            a[mi] = *(const frag16*)(As + (mi * 16 + lane15) * 32 + quad * 8);
#pragma unroll
        for (int ni = 0; ni < 2; ni++)
            b[ni] = *(const frag16*)(Bs + (wn + ni * 16 + lane15) * 32 + quad * 8);
#pragma unroll
        for (int mi = 0; mi < 4; mi++)
#pragma unroll
            for (int ni = 0; ni < 2; ni++)
                acc[mi][ni] = __builtin_amdgcn_mfma_f32_16x16x32_bf16(
                    a[mi], b[ni], acc[mi][ni], 0, 0, 0);
    }

#pragma unroll
    for (int ni = 0; ni < 2; ni++) {
        const int col = bn + wn + ni * 16 + lane15;
        const float bv = bo[col];
#pragma unroll
        for (int mi = 0; mi < 4; mi++) {
            const int row = bm + mi * 16 + quad * 4;
#pragma unroll
            for (int r = 0; r < 4; r++)
                out[(size_t)(row + r) * SIZE + col] = acc[mi][ni][r] + bv;
        }
    }
}

extern "C" void kernel_launch(void* const* d_in, const int* in_sizes, int n_in,
                              void* d_out, int out_size, void* d_ws, size_t ws_size,
                              hipStream_t stream) {
    const float* q  = (const float*)d_in[0];
    const float* k  = (const float*)d_in[1];
    const float* v  = (const float*)d_in[2];
    const float* Wq = (const float*)d_in[3];
    const float* bq = (const float*)d_in[4];
    const float* Wk = (const float*)d_in[5];
    const float* bk = (const float*)d_in[6];
    const float* Wv = (const float*)d_in[7];
    const float* bv = (const float*)d_in[8];
    const float* Wo = (const float*)d_in[9];
    const float* bo = (const float*)d_in[10];
    float* out = (float*)d_out;

    // ws (bf16): Wb[4M] | qb | kb | vb | qh | kh | vt  (4.19M elems each)
    // aliases: po (8.39M) = qb+kb (dead after qkv); ctx = vb; pl = Wq slot
    bf16* Wb  = (bf16*)d_ws;
    bf16* qb  = Wb + (size_t)4 * SIZE * SIZE;
    bf16* kb  = qb + (size_t)MROWS * SIZE;
    bf16* vb  = kb + (size_t)MROWS * SIZE;
    bf16* qh  = vb + (size_t)MROWS * SIZE;
    bf16* kh  = qh + (size_t)MROWS * SIZE;
    bf16* vt  = kh + (size_t)MROWS * SIZE;
    bf16* po  = qb;
    bf16* ctx = vb;
    float* pl = (float*)Wb;

    cast_kernel<<<dim3(MROWS * SIZE / 2048, 1, 7), 256, 0, stream>>>(
        Wq, Wk, Wv, Wo, q, k, v, Wb, qb, kb, vb);
    qkv_proj_kernel<<<dim3(SIZE / 128, MROWS / 128, 3), 256, 0, stream>>>(
        qb, kb, vb, Wb, bq, bk, bv, qh, kh, vt);
    attn_kernel<<<dim3(NQT * 2, NH, BB), 256, 0, stream>>>(qh, kh, vt, po, pl);
    combine_kernel<<<dim3(SS / 128, NH, BB), 256, 0, stream>>>(po, pl, ctx);
    out_proj_kernel<<<dim3(SIZE / 128, MROWS / 64, 1), 256, 0, stream>>>(
        ctx, Wb + (size_t)3 * SIZE * SIZE, bo, out);
}